// Round 2
// baseline (22292.563 us; speedup 1.0000x reference)
//
#include <hip/hip_runtime.h>
#include <hip/hip_bf16.h>

// QLSTM: T=512, B=256, D=128, H=256.  z = [x,h] @ W^T + b, W=[4H,384]
// Round 1: ONE persistent cooperative kernel for all 512 steps.
// 256 blocks (1/CU), block = 16 batches x 16 hidden j x 4 gates (wave g = gate g).
// W tile staged to LDS once; c-state in registers; per-step grid sync via
// pre-zeroed per-step counters + device-scope fences. hs is time-indexed
// (no WAR hazard -> one barrier per step).

#define T_STEPS 512
#define BATCH   256
#define DIN     128
#define HID     256
#define KDIM    384
#define LDK     392   // padded LDS row stride
#define GRIDN   256

typedef __attribute__((ext_vector_type(8))) short short8;
typedef __attribute__((ext_vector_type(4))) short short4v;
typedef __attribute__((ext_vector_type(4))) float f32x4;

__device__ __forceinline__ unsigned short f2bf(float f) {
    unsigned u = __float_as_uint(f);
    unsigned r = (u + 0x7FFFu + ((u >> 16) & 1u)) >> 16;
    return (unsigned short)r;
}
__device__ __forceinline__ float bf2f(unsigned short s) {
    return __uint_as_float(((unsigned)s) << 16);
}

// ---- pack weights: Wpack[n][k] bf16, n = g*256 + j, row-major [1024][384] ----
__global__ __launch_bounds__(256) void pack_w(
    const float* __restrict__ Wf, const float* __restrict__ Wi,
    const float* __restrict__ Wg, const float* __restrict__ Wo,
    unsigned short* __restrict__ Wp) {
    int idx = blockIdx.x * 256 + threadIdx.x;
    int n = idx / KDIM;
    int k = idx - n * KDIM;
    int g = n >> 8, j = n & 255;
    const float* s = (g == 0) ? Wf : (g == 1) ? Wi : (g == 2) ? Wg : Wo;
    Wp[idx] = f2bf(s[j * KDIM + k]);
}

__global__ __launch_bounds__(256) void pack_b(
    const float* __restrict__ bf, const float* __restrict__ bi,
    const float* __restrict__ bg, const float* __restrict__ bo,
    float* __restrict__ bp) {
    int n = blockIdx.x * 256 + threadIdx.x;
    int g = n >> 8, j = n & 255;
    const float* s = (g == 0) ? bf : (g == 1) ? bi : (g == 2) ? bg : bo;
    bp[n] = s[j];
}

// ---- zero h0 (bf16) and the per-step barrier counters ----
__global__ __launch_bounds__(256) void init_k(
    unsigned short* __restrict__ hs, int* __restrict__ bar) {
    int tid = blockIdx.x * 256 + threadIdx.x;   // grid 256 -> 65536
    hs[tid] = 0;
    if (tid < T_STEPS) bar[tid] = 0;
}

// ---- persistent LSTM: all 512 steps in one launch ----
__global__ __launch_bounds__(256, 1) void lstm_persist(
    const float* __restrict__ X,            // [T,B,D] fp32
    const unsigned short* __restrict__ W,   // [1024][384] bf16
    const float* __restrict__ bias,         // [1024]
    unsigned short* __restrict__ hs,        // [T+1][B][H] bf16
    float* __restrict__ out,                // full output buffer
    int* __restrict__ bar) {                // [T] counters, pre-zeroed
    __shared__ __align__(16) unsigned short W_s[64 * LDK];    // 50176 B, persistent
    __shared__ __align__(16) unsigned short comb_s[16 * LDK]; // 12544 B, per step
    __shared__ __align__(16) float z_s[4 * 272];              // 4352 B (stride 17)

    const int tid = threadIdx.x;
    const int bg = blockIdx.x >> 4, jg = blockIdx.x & 15;
    const int b0 = bg * 16, j0 = jg * 16;
    const int wave = tid >> 6, lane = tid & 63;
    const int l16 = lane & 15, quad = lane >> 4;
    const int bi = tid >> 4, jj = tid & 15;
    const int b = b0 + bi, j = j0 + jj;

    // stage W tile once: local row = g*16+jj <- global row g*256+j0+jj ; 64x384
#pragma unroll
    for (int c = 0; c < 12; ++c) {
        int q = c * 256 + tid;
        int row = q / 48, c8 = q - row * 48;
        int g = row >> 4, jr = row & 15;
        short8 v = *(const short8*)(W + ((g * 256 + j0 + jr) * KDIM + c8 * 8));
        *(short8*)(&W_s[row * LDK + c8 * 8]) = v;
    }
    // per-thread bias for the 4 gates of hidden unit j
    const float bs0 = bias[0 * HID + j];
    const float bs1 = bias[1 * HID + j];
    const float bs2 = bias[2 * HID + j];
    const float bs3 = bias[3 * HID + j];

    float c_reg = 0.f;
    float h_final = 0.f;

    const unsigned short* arow = &comb_s[l16 * LDK + quad * 8];
    const unsigned short* brow = &W_s[(wave * 16 + l16) * LDK + quad * 8];

    __syncthreads();

    for (int t = 0; t < T_STEPS; ++t) {
        // ---- stage combined [x | h] for this step ----
        const float* xbase = X + (size_t)t * BATCH * DIN + b0 * DIN;
#pragma unroll
        for (int c = 0; c < 2; ++c) {
            int q = c * 256 + tid;              // 512 float4 chunks
            int row = q >> 5, c4 = q & 31;
            const float4 v = *(const float4*)(xbase + row * DIN + c4 * 4);
            short4v r;
            r.x = (short)f2bf(v.x); r.y = (short)f2bf(v.y);
            r.z = (short)f2bf(v.z); r.w = (short)f2bf(v.w);
            *(short4v*)(&comb_s[row * LDK + c4 * 4]) = r;
        }
        const unsigned short* hprev = hs + ((size_t)t << 16) + b0 * HID;
#pragma unroll
        for (int c = 0; c < 2; ++c) {
            int q = c * 256 + tid;              // 512 ushort8 chunks
            int row = q >> 5, c8 = q & 31;
            short8 v = *(const short8*)(hprev + row * HID + c8 * 8);
            *(short8*)(&comb_s[row * LDK + DIN + c8 * 8]) = v;
        }
        __syncthreads();

        // ---- MFMA: wave computes z_gate = comb[16x384] * Wg^T, 2 acc chains ----
        f32x4 acc0 = {0.f, 0.f, 0.f, 0.f}, acc1 = {0.f, 0.f, 0.f, 0.f};
#pragma unroll
        for (int kt = 0; kt < 6; ++kt) {
            short8 a0 = *(const short8*)(arow + (2 * kt) * 32);
            short8 b0v = *(const short8*)(brow + (2 * kt) * 32);
            short8 a1 = *(const short8*)(arow + (2 * kt + 1) * 32);
            short8 b1v = *(const short8*)(brow + (2 * kt + 1) * 32);
            acc0 = __builtin_amdgcn_mfma_f32_16x16x32_bf16(a0, b0v, acc0, 0, 0, 0);
            acc1 = __builtin_amdgcn_mfma_f32_16x16x32_bf16(a1, b1v, acc1, 0, 0, 0);
        }
#pragma unroll
        for (int r = 0; r < 4; ++r)
            z_s[wave * 272 + (quad * 4 + r) * 17 + l16] = acc0[r] + acc1[r];
        __syncthreads();

        // ---- elementwise gate math; c-state stays in this register ----
        float zf = z_s[0 * 272 + bi * 17 + jj] + bs0;
        float zi = z_s[1 * 272 + bi * 17 + jj] + bs1;
        float zg = z_s[2 * 272 + bi * 17 + jj] + bs2;
        float zo = z_s[3 * 272 + bi * 17 + jj] + bs3;
        float fg = 1.f / (1.f + expf(-zf));
        float ig = 1.f / (1.f + expf(-zi));
        float gg = tanhf(zg);
        float og = 1.f / (1.f + expf(-zo));
        c_reg = fg * c_reg + ig * gg;
        float hval = og * tanhf(c_reg);
        hs[((size_t)(t + 1) << 16) + b * HID + j] = f2bf(hval);
        if (t == T_STEPS - 1) h_final = hval;

        // ---- grid barrier (skip after last step) ----
        if (t < T_STEPS - 1) {
            __threadfence();        // release: drain my h store to coherence point
            __syncthreads();
            if (tid == 0) {
                atomicAdd(&bar[t], 1);
                while (__hip_atomic_load(&bar[t], __ATOMIC_RELAXED,
                                         __HIP_MEMORY_SCOPE_AGENT) < GRIDN)
                    __builtin_amdgcn_s_sleep(1);
            }
            __syncthreads();
            __threadfence();        // acquire: invalidate stale L1/L2 lines
        }
    }

    // epilogue: hx (fp32) and cx outputs
    out[T_STEPS * BATCH * 2 + b * HID + j] = h_final;
    out[T_STEPS * BATCH * 2 + BATCH * HID + b * HID + j] = c_reg;
}

// ---- classifier head: one wave per (t,b) row ----
__global__ __launch_bounds__(256) void probs_k(
    const unsigned short* __restrict__ hs, const float* __restrict__ Wc,
    const float* __restrict__ bc, float* __restrict__ out) {
    const int wave = threadIdx.x >> 6, lane = threadIdx.x & 63;
    const size_t row = (size_t)blockIdx.x * 4 + wave;   // row = t*256+b < 131072
    const unsigned short* h = hs + (size_t)BATCH * HID + row * HID;
    short4v hv = *(const short4v*)(h + lane * 4);
    const float4 wv = *(const float4*)(Wc + lane * 4);
    float p = bf2f((unsigned short)hv.x) * wv.x + bf2f((unsigned short)hv.y) * wv.y +
              bf2f((unsigned short)hv.z) * wv.z + bf2f((unsigned short)hv.w) * wv.w;
#pragma unroll
    for (int off = 32; off >= 1; off >>= 1) p += __shfl_down(p, off);
    if (lane == 0) {
        float prob = 1.f / (1.f + expf(-(p + bc[0])));
        out[row * 2]     = prob;
        out[row * 2 + 1] = 1.f - prob;
    }
}

extern "C" void kernel_launch(void* const* d_in, const int* in_sizes, int n_in,
                              void* d_out, int out_size, void* d_ws, size_t ws_size,
                              hipStream_t stream) {
    const float* X  = (const float*)d_in[0];
    const float* Wf = (const float*)d_in[1];
    const float* bfp= (const float*)d_in[2];
    const float* Wi = (const float*)d_in[3];
    const float* bip= (const float*)d_in[4];
    const float* Wg = (const float*)d_in[5];
    const float* bgp= (const float*)d_in[6];
    const float* Wo = (const float*)d_in[7];
    const float* bop= (const float*)d_in[8];
    const float* Wc = (const float*)d_in[9];
    const float* bc = (const float*)d_in[10];
    float* out = (float*)d_out;

    char* ws = (char*)d_ws;
    unsigned short* Wpack = (unsigned short*)(ws);               // 786432 B
    float* bias = (float*)(ws + 786432);                         // 4096 B
    int* bar    = (int*)(ws + 790528);                           // 2048 B
    unsigned short* hs = (unsigned short*)(ws + 802816);         // (T+1)*B*H*2

    pack_w<<<1536, 256, 0, stream>>>(Wf, Wi, Wg, Wo, Wpack);
    pack_b<<<4, 256, 0, stream>>>(bfp, bip, bgp, bop, bias);
    init_k<<<256, 256, 0, stream>>>(hs, bar);

    void* kargs[6] = {(void*)&X, (void*)&Wpack, (void*)&bias,
                      (void*)&hs, (void*)&out, (void*)&bar};
    hipLaunchCooperativeKernel((const void*)lstm_persist, dim3(GRIDN), dim3(256),
                               kargs, 0, stream);

    probs_k<<<32768, 256, 0, stream>>>(hs, Wc, bc, out);
}

// Round 3
// 1844.146 us; speedup vs baseline: 12.0883x; 12.0883x over previous
//
#include <hip/hip_runtime.h>
#include <hip/hip_bf16.h>

// QLSTM: T=512, B=256, D=128, H=256.  z = [x,h] @ W^T + b, W=[4H,384]
// Round 2: persistent cooperative kernel, NO cache-flushing fences.
// h exchange goes through device-scope (sc1) stores/loads only; X/W stay in
// normal cached paths. Barrier domain shrunk to the 16 blocks sharing a
// batch-group (bg): block (bg,jg) only needs h[bg rows, all j].

#define T_STEPS 512
#define BATCH   256
#define DIN     128
#define HID     256
#define KDIM    384
#define LDK     392   // padded LDS row stride (shorts)
#define GRIDN   256
#define BARSTR  520   // per-bg counter stride (ints) -> distinct cache lines

typedef __attribute__((ext_vector_type(8))) short short8;
typedef __attribute__((ext_vector_type(4))) short short4v;
typedef __attribute__((ext_vector_type(4))) float f32x4;

__device__ __forceinline__ unsigned short f2bf(float f) {
    unsigned u = __float_as_uint(f);
    unsigned r = (u + 0x7FFFu + ((u >> 16) & 1u)) >> 16;
    return (unsigned short)r;
}
__device__ __forceinline__ float bf2f(unsigned short s) {
    return __uint_as_float(((unsigned)s) << 16);
}
__device__ __forceinline__ float sigmoid_f(float x) {
    return 1.f / (1.f + __expf(-x));
}
__device__ __forceinline__ float tanh_f(float x) {
    float e = __expf(2.f * x);           // inf-safe: x>>0 -> 1, x<<0 -> -1
    return 1.f - 2.f / (e + 1.f);
}
// two 16B device-coherent loads, one latency
__device__ __forceinline__ void load2_sc1(const unsigned short* p0,
                                          const unsigned short* p1,
                                          uint4& r0, uint4& r1) {
    asm volatile(
        "global_load_dwordx4 %0, %2, off sc1\n\t"
        "global_load_dwordx4 %1, %3, off sc1\n\t"
        "s_waitcnt vmcnt(0)"
        : "=&v"(r0), "=&v"(r1)
        : "v"(p0), "v"(p1)
        : "memory");
}
__device__ __forceinline__ void waitcnt_vm0() {
    asm volatile("s_waitcnt vmcnt(0)" ::: "memory");
}

// ---- pack weights: Wpack[n][k] bf16, n = g*256 + j, row-major [1024][384] ----
__global__ __launch_bounds__(256) void pack_w(
    const float* __restrict__ Wf, const float* __restrict__ Wi,
    const float* __restrict__ Wg, const float* __restrict__ Wo,
    unsigned short* __restrict__ Wp) {
    int idx = blockIdx.x * 256 + threadIdx.x;
    int n = idx / KDIM;
    int k = idx - n * KDIM;
    int g = n >> 8, j = n & 255;
    const float* s = (g == 0) ? Wf : (g == 1) ? Wi : (g == 2) ? Wg : Wo;
    Wp[idx] = f2bf(s[j * KDIM + k]);
}

__global__ __launch_bounds__(256) void pack_b(
    const float* __restrict__ bf, const float* __restrict__ bi,
    const float* __restrict__ bg, const float* __restrict__ bo,
    float* __restrict__ bp) {
    int n = blockIdx.x * 256 + threadIdx.x;
    int g = n >> 8, j = n & 255;
    const float* s = (g == 0) ? bf : (g == 1) ? bi : (g == 2) ? bg : bo;
    bp[n] = s[j];
}

// ---- zero h0 (bf16) and the per-(bg,t) barrier counters ----
__global__ __launch_bounds__(256) void init_k(
    unsigned short* __restrict__ hs, int* __restrict__ bar) {
    int tid = blockIdx.x * 256 + threadIdx.x;   // grid 256 -> 65536
    hs[tid] = 0;
    if (tid < 16 * BARSTR) bar[tid] = 0;
}

// ---- persistent LSTM: all 512 steps in one launch ----
__global__ __launch_bounds__(256, 1) void lstm_persist(
    const float* __restrict__ X,            // [T,B,D] fp32
    const unsigned short* __restrict__ W,   // [1024][384] bf16
    const float* __restrict__ bias,         // [1024]
    unsigned short* __restrict__ hs,        // [T+1][B][H] bf16
    float* __restrict__ out,                // full output buffer
    int* __restrict__ bar) {                // [16][BARSTR] counters, pre-zeroed
    __shared__ __align__(16) unsigned short W_s[64 * LDK];    // 50176 B
    __shared__ __align__(16) unsigned short comb_s[16 * LDK]; // 12544 B
    __shared__ __align__(16) float z_s[4 * 272];              // 4352 B

    const int tid = threadIdx.x;
    const int bg = blockIdx.x >> 4, jg = blockIdx.x & 15;
    const int b0 = bg * 16, j0 = jg * 16;
    const int wave = tid >> 6, lane = tid & 63;
    const int l16 = lane & 15, quad = lane >> 4;
    const int bi = tid >> 4, jj = tid & 15;
    const int b = b0 + bi, j = j0 + jj;
    int* mybar = bar + bg * BARSTR;

    // stage W tile once: local row = g*16+jr <- global row g*256+j0+jr ; 64x384
#pragma unroll
    for (int c = 0; c < 12; ++c) {
        int q = c * 256 + tid;
        int row = q / 48, c8 = q - row * 48;
        int g = row >> 4, jr = row & 15;
        short8 v = *(const short8*)(W + ((g * 256 + j0 + jr) * KDIM + c8 * 8));
        *(short8*)(&W_s[row * LDK + c8 * 8]) = v;
    }
    const float bs0 = bias[0 * HID + j];
    const float bs1 = bias[1 * HID + j];
    const float bs2 = bias[2 * HID + j];
    const float bs3 = bias[3 * HID + j];

    float c_reg = 0.f;
    float h_final = 0.f;

    const unsigned short* arow = &comb_s[l16 * LDK + quad * 8];
    const unsigned short* brow = &W_s[(wave * 16 + l16) * LDK + quad * 8];
    // h staging mapping: thread q -> row=q>>4 (of 16), c16=q&15 (16B chunk)
    const int hrow = tid >> 4, hc = tid & 15;

    __syncthreads();

    for (int t = 0; t < T_STEPS; ++t) {
        // ---- A: stage x_t (cached) and h_{t-1} (device-coherent) ----
        const float* xbase = X + (size_t)t * BATCH * DIN + b0 * DIN;
        const float4 xv0 = *(const float4*)(xbase + (tid >> 5) * DIN + (tid & 31) * 4);
        const float4 xv1 = *(const float4*)(xbase + ((tid + 256) >> 5) * DIN + (tid & 31) * 4);
        const unsigned short* hprev = hs + ((size_t)t << 16) + b0 * HID;
        uint4 h0, h1;
        load2_sc1(hprev + hrow * HID + hc * 8,
                  hprev + hrow * HID + 128 + hc * 8, h0, h1);
        {
            int row = tid >> 5, c4 = tid & 31;
            short4v r;
            r.x = (short)f2bf(xv0.x); r.y = (short)f2bf(xv0.y);
            r.z = (short)f2bf(xv0.z); r.w = (short)f2bf(xv0.w);
            *(short4v*)(&comb_s[row * LDK + c4 * 4]) = r;
            row = (tid + 256) >> 5;
            r.x = (short)f2bf(xv1.x); r.y = (short)f2bf(xv1.y);
            r.z = (short)f2bf(xv1.z); r.w = (short)f2bf(xv1.w);
            *(short4v*)(&comb_s[row * LDK + c4 * 4]) = r;
        }
        *(uint4*)(&comb_s[hrow * LDK + DIN + hc * 8]) = h0;
        *(uint4*)(&comb_s[hrow * LDK + DIN + 128 + hc * 8]) = h1;
        __syncthreads();

        // ---- B: MFMA z_gate = comb[16x384] * Wg^T, 2 acc chains ----
        f32x4 acc0 = {0.f, 0.f, 0.f, 0.f}, acc1 = {0.f, 0.f, 0.f, 0.f};
#pragma unroll
        for (int kt = 0; kt < 6; ++kt) {
            short8 a0 = *(const short8*)(arow + (2 * kt) * 32);
            short8 b0v = *(const short8*)(brow + (2 * kt) * 32);
            short8 a1 = *(const short8*)(arow + (2 * kt + 1) * 32);
            short8 b1v = *(const short8*)(brow + (2 * kt + 1) * 32);
            acc0 = __builtin_amdgcn_mfma_f32_16x16x32_bf16(a0, b0v, acc0, 0, 0, 0);
            acc1 = __builtin_amdgcn_mfma_f32_16x16x32_bf16(a1, b1v, acc1, 0, 0, 0);
        }
#pragma unroll
        for (int r = 0; r < 4; ++r)
            z_s[wave * 272 + (quad * 4 + r) * 17 + l16] = acc0[r] + acc1[r];
        __syncthreads();

        // ---- C: gates; c-state in register; h store device-coherent ----
        float zf = z_s[0 * 272 + bi * 17 + jj] + bs0;
        float zi = z_s[1 * 272 + bi * 17 + jj] + bs1;
        float zg = z_s[2 * 272 + bi * 17 + jj] + bs2;
        float zo = z_s[3 * 272 + bi * 17 + jj] + bs3;
        float fg = sigmoid_f(zf);
        float ig = sigmoid_f(zi);
        float gg = tanh_f(zg);
        float og = sigmoid_f(zo);
        c_reg = fg * c_reg + ig * gg;
        float hval = og * tanh_f(c_reg);
        __hip_atomic_store(&hs[((size_t)(t + 1) << 16) + b * HID + j], f2bf(hval),
                           __ATOMIC_RELAXED, __HIP_MEMORY_SCOPE_AGENT);
        if (t == T_STEPS - 1) h_final = hval;

        // ---- D: bg-group barrier (16 blocks), no cache maintenance ----
        if (t < T_STEPS - 1) {
            waitcnt_vm0();               // my wave's h stores at coherence point
            __syncthreads();             // all waves drained
            if (tid == 0) atomicAdd(&mybar[t], 1);
            while (__hip_atomic_load(&mybar[t], __ATOMIC_RELAXED,
                                     __HIP_MEMORY_SCOPE_AGENT) < 16) {}
            // waves proceed independently; pre-MFMA syncthreads re-converges
        }
    }

    // epilogue: hx (fp32) and cx outputs
    out[T_STEPS * BATCH * 2 + b * HID + j] = h_final;
    out[T_STEPS * BATCH * 2 + BATCH * HID + b * HID + j] = c_reg;
}

// ---- classifier head: one wave per (t,b) row ----
__global__ __launch_bounds__(256) void probs_k(
    const unsigned short* __restrict__ hs, const float* __restrict__ Wc,
    const float* __restrict__ bc, float* __restrict__ out) {
    const int wave = threadIdx.x >> 6, lane = threadIdx.x & 63;
    const size_t row = (size_t)blockIdx.x * 4 + wave;   // row = t*256+b < 131072
    const unsigned short* h = hs + (size_t)BATCH * HID + row * HID;
    short4v hv = *(const short4v*)(h + lane * 4);
    const float4 wv = *(const float4*)(Wc + lane * 4);
    float p = bf2f((unsigned short)hv.x) * wv.x + bf2f((unsigned short)hv.y) * wv.y +
              bf2f((unsigned short)hv.z) * wv.z + bf2f((unsigned short)hv.w) * wv.w;
#pragma unroll
    for (int off = 32; off >= 1; off >>= 1) p += __shfl_down(p, off);
    if (lane == 0) {
        float prob = 1.f / (1.f + __expf(-(p + bc[0])));
        out[row * 2]     = prob;
        out[row * 2 + 1] = 1.f - prob;
    }
}

extern "C" void kernel_launch(void* const* d_in, const int* in_sizes, int n_in,
                              void* d_out, int out_size, void* d_ws, size_t ws_size,
                              hipStream_t stream) {
    const float* X  = (const float*)d_in[0];
    const float* Wf = (const float*)d_in[1];
    const float* bfp= (const float*)d_in[2];
    const float* Wi = (const float*)d_in[3];
    const float* bip= (const float*)d_in[4];
    const float* Wg = (const float*)d_in[5];
    const float* bgp= (const float*)d_in[6];
    const float* Wo = (const float*)d_in[7];
    const float* bop= (const float*)d_in[8];
    const float* Wc = (const float*)d_in[9];
    const float* bc = (const float*)d_in[10];
    float* out = (float*)d_out;

    char* ws = (char*)d_ws;
    unsigned short* Wpack = (unsigned short*)(ws);               // 786432 B
    float* bias = (float*)(ws + 786432);                         // 4096 B
    int* bar    = (int*)(ws + 790528);                           // 16*520*4 = 33280 B
    unsigned short* hs = (unsigned short*)(ws + 827392);         // (T+1)*B*H*2

    pack_w<<<1536, 256, 0, stream>>>(Wf, Wi, Wg, Wo, Wpack);
    pack_b<<<4, 256, 0, stream>>>(bfp, bip, bgp, bop, bias);
    init_k<<<256, 256, 0, stream>>>(hs, bar);

    void* kargs[6] = {(void*)&X, (void*)&Wpack, (void*)&bias,
                      (void*)&hs, (void*)&out, (void*)&bar};
    hipLaunchCooperativeKernel((const void*)lstm_persist, dim3(GRIDN), dim3(256),
                               kargs, 0, stream);

    probs_k<<<32768, 256, 0, stream>>>(hs, Wc, bc, out);
}

// Round 4
// 1304.460 us; speedup vs baseline: 17.0895x; 1.4137x over previous
//
#include <hip/hip_runtime.h>
#include <hip/hip_bf16.h>

// QLSTM: T=512, B=256, D=128, H=256.  z = [x,h] @ W^T + b, W=[4H,384]
// Round 4: barrier FUSED into the data. h is exchanged as u32 = (bf16<<16)|tag;
// consumers spin-read the exact words they need (sc1) until tags are fresh.
// No atomics, no flags, no separate post-barrier load. Double-buffered by step
// parity (512 KB, L3-resident). h history for the classifier head goes to a
// separate plain cached store. x_{t+1} prefetched into regs during gate phase.

#define T_STEPS 512
#define BATCH   256
#define DIN     128
#define HID     256
#define KDIM    384
#define LDK     392   // padded LDS row stride (shorts)
#define GRIDN   256

typedef __attribute__((ext_vector_type(8))) short short8;
typedef __attribute__((ext_vector_type(4))) short short4v;
typedef __attribute__((ext_vector_type(4))) float f32x4;

__device__ __forceinline__ unsigned short f2bf(float f) {
    unsigned u = __float_as_uint(f);
    unsigned r = (u + 0x7FFFu + ((u >> 16) & 1u)) >> 16;
    return (unsigned short)r;
}
__device__ __forceinline__ float bf2f(unsigned short s) {
    return __uint_as_float(((unsigned)s) << 16);
}
__device__ __forceinline__ float sigmoid_f(float x) {
    return 1.f / (1.f + __expf(-x));
}
__device__ __forceinline__ float tanh_f(float x) {
    float e = __expf(2.f * x);
    return 1.f - 2.f / (e + 1.f);
}
// 64B device-coherent poll read (4 x dwordx4, one latency)
__device__ __forceinline__ void poll_load64(const unsigned int* p, uint4& a,
                                            uint4& b, uint4& c, uint4& d) {
    asm volatile(
        "global_load_dwordx4 %0, %4, off sc1\n\t"
        "global_load_dwordx4 %1, %4, off offset:16 sc1\n\t"
        "global_load_dwordx4 %2, %4, off offset:32 sc1\n\t"
        "global_load_dwordx4 %3, %4, off offset:48 sc1\n\t"
        "s_waitcnt vmcnt(0)"
        : "=&v"(a), "=&v"(b), "=&v"(c), "=&v"(d)
        : "v"(p)
        : "memory");
}
__device__ __forceinline__ void store_sc1_u32(unsigned int* p, unsigned int v) {
    asm volatile("global_store_dword %0, %1, off sc1" :: "v"(p), "v"(v) : "memory");
}
__device__ __forceinline__ unsigned pack2bf(unsigned lo, unsigned hi) {
    return (hi & 0xFFFF0000u) | (lo >> 16);
}

// ---- pack weights: Wpack[n][k] bf16, n = g*256 + j, row-major [1024][384] ----
__global__ __launch_bounds__(256) void pack_w(
    const float* __restrict__ Wf, const float* __restrict__ Wi,
    const float* __restrict__ Wg, const float* __restrict__ Wo,
    unsigned short* __restrict__ Wp) {
    int idx = blockIdx.x * 256 + threadIdx.x;
    int n = idx / KDIM;
    int k = idx - n * KDIM;
    int g = n >> 8, j = n & 255;
    const float* s = (g == 0) ? Wf : (g == 1) ? Wi : (g == 2) ? Wg : Wo;
    Wp[idx] = f2bf(s[j * KDIM + k]);
}

__global__ __launch_bounds__(256) void pack_b(
    const float* __restrict__ bf, const float* __restrict__ bi,
    const float* __restrict__ bg, const float* __restrict__ bo,
    float* __restrict__ bp) {
    int n = blockIdx.x * 256 + threadIdx.x;
    int g = n >> 8, j = n & 255;
    const float* s = (g == 0) ? bf : (g == 1) ? bi : (g == 2) ? bg : bo;
    bp[n] = s[j];
}

// ---- zero both parity exchange buffers (h_0 = 0 with tag 0) ----
__global__ __launch_bounds__(256) void init_k(unsigned int* __restrict__ hxp) {
    int tid = blockIdx.x * 256 + threadIdx.x;   // grid 256 -> 65536
    hxp[tid] = 0u;
    hxp[65536 + tid] = 0u;
}

// ---- persistent LSTM: all 512 steps in one launch ----
__global__ __launch_bounds__(256, 1) void lstm_persist(
    const float* __restrict__ X,            // [T,B,D] fp32
    const unsigned short* __restrict__ W,   // [1024][384] bf16
    const float* __restrict__ bias,         // [1024]
    unsigned int* __restrict__ hxp,         // [2][B][H] u32 (bf16|tag), pre-zeroed
    unsigned short* __restrict__ hist,      // [T][B][H] bf16 (h_1..h_512)
    float* __restrict__ out) {
    __shared__ __align__(16) unsigned short W_s[64 * LDK];    // 50176 B
    __shared__ __align__(16) unsigned short comb_s[16 * LDK]; // 12544 B
    __shared__ __align__(16) float z_s[4 * 272];              // 4352 B

    const int tid = threadIdx.x;
    const int bg = blockIdx.x >> 4, jg = blockIdx.x & 15;
    const int b0 = bg * 16, j0 = jg * 16;
    const int wave = tid >> 6, lane = tid & 63;
    const int l16 = lane & 15, quad = lane >> 4;
    const int bi = tid >> 4, jj = tid & 15;
    const int b = b0 + bi, j = j0 + jj;

    // stage W tile once: local row = g*16+jr <- global row g*256+j0+jr ; 64x384
#pragma unroll
    for (int c = 0; c < 12; ++c) {
        int q = c * 256 + tid;
        int row = q / 48, c8 = q - row * 48;
        int g = row >> 4, jr = row & 15;
        short8 v = *(const short8*)(W + ((g * 256 + j0 + jr) * KDIM + c8 * 8));
        *(short8*)(&W_s[row * LDK + c8 * 8]) = v;
    }
    const float bs0 = bias[0 * HID + j];
    const float bs1 = bias[1 * HID + j];
    const float bs2 = bias[2 * HID + j];
    const float bs3 = bias[3 * HID + j];

    float c_reg = 0.f;
    float h_final = 0.f;

    const unsigned short* arow = &comb_s[l16 * LDK + quad * 8];
    const unsigned short* brow = &W_s[(wave * 16 + l16) * LDK + quad * 8];
    // poll mapping: thread covers row hrow (16 batches), 16 j-words at hc*16
    const int hrow = tid >> 4, hc = tid & 15;
    // x staging mapping (2 chunks per thread)
    const int xr0 = tid >> 5, xc4 = tid & 31, xr1 = (tid + 256) >> 5;

    // prefetch x_0
    const float* xb = X + b0 * DIN;
    float4 xv0 = *(const float4*)(xb + xr0 * DIN + xc4 * 4);
    float4 xv1 = *(const float4*)(xb + xr1 * DIN + xc4 * 4);

    __syncthreads();

    for (int k = 0; k < T_STEPS; ++k) {
        // ---- stage x_k from prefetched regs ----
        {
            short4v r;
            r.x = (short)f2bf(xv0.x); r.y = (short)f2bf(xv0.y);
            r.z = (short)f2bf(xv0.z); r.w = (short)f2bf(xv0.w);
            *(short4v*)(&comb_s[xr0 * LDK + xc4 * 4]) = r;
            r.x = (short)f2bf(xv1.x); r.y = (short)f2bf(xv1.y);
            r.z = (short)f2bf(xv1.z); r.w = (short)f2bf(xv1.w);
            *(short4v*)(&comb_s[xr1 * LDK + xc4 * 4]) = r;
        }

        // ---- poll h_k (tags == k) : data IS the barrier ----
        const unsigned int* hbase =
            hxp + (k & 1) * 65536 + (b0 + hrow) * HID + hc * 16;
        uint4 a, bq, cq, d;
        const unsigned tag = (unsigned)k;
        for (;;) {
            poll_load64(hbase, a, bq, cq, d);
            bool fresh =
                ((a.x  ^ tag) & 0xFFFFu) == 0 && ((a.y  ^ tag) & 0xFFFFu) == 0 &&
                ((a.z  ^ tag) & 0xFFFFu) == 0 && ((a.w  ^ tag) & 0xFFFFu) == 0 &&
                ((bq.x ^ tag) & 0xFFFFu) == 0 && ((bq.y ^ tag) & 0xFFFFu) == 0 &&
                ((bq.z ^ tag) & 0xFFFFu) == 0 && ((bq.w ^ tag) & 0xFFFFu) == 0 &&
                ((cq.x ^ tag) & 0xFFFFu) == 0 && ((cq.y ^ tag) & 0xFFFFu) == 0 &&
                ((cq.z ^ tag) & 0xFFFFu) == 0 && ((cq.w ^ tag) & 0xFFFFu) == 0 &&
                ((d.x  ^ tag) & 0xFFFFu) == 0 && ((d.y  ^ tag) & 0xFFFFu) == 0 &&
                ((d.z  ^ tag) & 0xFFFFu) == 0 && ((d.w  ^ tag) & 0xFFFFu) == 0;
            if (__all(fresh)) break;
            __builtin_amdgcn_s_sleep(2);
        }
        // extract 16 bf16 -> comb_s[hrow][DIN + hc*16 ..]
        {
            uint4 p0, p1;
            p0.x = pack2bf(a.x, a.y);  p0.y = pack2bf(a.z, a.w);
            p0.z = pack2bf(bq.x, bq.y); p0.w = pack2bf(bq.z, bq.w);
            p1.x = pack2bf(cq.x, cq.y); p1.y = pack2bf(cq.z, cq.w);
            p1.z = pack2bf(d.x, d.y);  p1.w = pack2bf(d.z, d.w);
            *(uint4*)(&comb_s[hrow * LDK + DIN + hc * 16]) = p0;
            *(uint4*)(&comb_s[hrow * LDK + DIN + hc * 16 + 8]) = p1;
        }
        __syncthreads();

        // ---- MFMA: z_gate = comb[16x384] * Wg^T, 2 acc chains ----
        f32x4 acc0 = {0.f, 0.f, 0.f, 0.f}, acc1 = {0.f, 0.f, 0.f, 0.f};
#pragma unroll
        for (int kt = 0; kt < 6; ++kt) {
            short8 a0 = *(const short8*)(arow + (2 * kt) * 32);
            short8 b0v = *(const short8*)(brow + (2 * kt) * 32);
            short8 a1 = *(const short8*)(arow + (2 * kt + 1) * 32);
            short8 b1v = *(const short8*)(brow + (2 * kt + 1) * 32);
            acc0 = __builtin_amdgcn_mfma_f32_16x16x32_bf16(a0, b0v, acc0, 0, 0, 0);
            acc1 = __builtin_amdgcn_mfma_f32_16x16x32_bf16(a1, b1v, acc1, 0, 0, 0);
        }
#pragma unroll
        for (int r = 0; r < 4; ++r)
            z_s[wave * 272 + (quad * 4 + r) * 17 + l16] = acc0[r] + acc1[r];
        __syncthreads();

        // ---- prefetch x_{k+1} (off critical path, overlaps gates) ----
        if (k + 1 < T_STEPS) {
            const float* xn = X + (size_t)(k + 1) * BATCH * DIN + b0 * DIN;
            xv0 = *(const float4*)(xn + xr0 * DIN + xc4 * 4);
            xv1 = *(const float4*)(xn + xr1 * DIN + xc4 * 4);
        }

        // ---- gates; c in register; h out: packed sc1 + plain history ----
        float zf = z_s[0 * 272 + bi * 17 + jj] + bs0;
        float zi = z_s[1 * 272 + bi * 17 + jj] + bs1;
        float zg = z_s[2 * 272 + bi * 17 + jj] + bs2;
        float zo = z_s[3 * 272 + bi * 17 + jj] + bs3;
        float fg = sigmoid_f(zf);
        float ig = sigmoid_f(zi);
        float gg = tanh_f(zg);
        float og = sigmoid_f(zo);
        c_reg = fg * c_reg + ig * gg;
        float hval = og * tanh_f(c_reg);
        unsigned short hb = f2bf(hval);
        hist[(size_t)k * BATCH * HID + b * HID + j] = hb;   // for classifier head
        store_sc1_u32(hxp + ((k + 1) & 1) * 65536 + b * HID + j,
                      ((unsigned)hb << 16) | (unsigned)(k + 1));
        if (k == T_STEPS - 1) h_final = hval;
    }

    // epilogue: hx (fp32) and cx outputs
    out[T_STEPS * BATCH * 2 + b * HID + j] = h_final;
    out[T_STEPS * BATCH * 2 + BATCH * HID + b * HID + j] = c_reg;
}

// ---- classifier head: one wave per (t,b) row ----
__global__ __launch_bounds__(256) void probs_k(
    const unsigned short* __restrict__ hist, const float* __restrict__ Wc,
    const float* __restrict__ bc, float* __restrict__ out) {
    const int wave = threadIdx.x >> 6, lane = threadIdx.x & 63;
    const size_t row = (size_t)blockIdx.x * 4 + wave;   // row = t*256+b < 131072
    const unsigned short* h = hist + row * HID;
    short4v hv = *(const short4v*)(h + lane * 4);
    const float4 wv = *(const float4*)(Wc + lane * 4);
    float p = bf2f((unsigned short)hv.x) * wv.x + bf2f((unsigned short)hv.y) * wv.y +
              bf2f((unsigned short)hv.z) * wv.z + bf2f((unsigned short)hv.w) * wv.w;
#pragma unroll
    for (int off = 32; off >= 1; off >>= 1) p += __shfl_down(p, off);
    if (lane == 0) {
        float prob = 1.f / (1.f + __expf(-(p + bc[0])));
        out[row * 2]     = prob;
        out[row * 2 + 1] = 1.f - prob;
    }
}

extern "C" void kernel_launch(void* const* d_in, const int* in_sizes, int n_in,
                              void* d_out, int out_size, void* d_ws, size_t ws_size,
                              hipStream_t stream) {
    const float* X  = (const float*)d_in[0];
    const float* Wf = (const float*)d_in[1];
    const float* bfp= (const float*)d_in[2];
    const float* Wi = (const float*)d_in[3];
    const float* bip= (const float*)d_in[4];
    const float* Wg = (const float*)d_in[5];
    const float* bgp= (const float*)d_in[6];
    const float* Wo = (const float*)d_in[7];
    const float* bop= (const float*)d_in[8];
    const float* Wc = (const float*)d_in[9];
    const float* bc = (const float*)d_in[10];
    float* out = (float*)d_out;

    char* ws = (char*)d_ws;
    unsigned short* Wpack = (unsigned short*)(ws);               // 786432 B
    float* bias = (float*)(ws + 786432);                         // 4096 B
    unsigned int* hxp = (unsigned int*)(ws + 790528);            // 524288 B
    unsigned short* hist = (unsigned short*)(ws + 1314816);      // 67108864 B

    pack_w<<<1536, 256, 0, stream>>>(Wf, Wi, Wg, Wo, Wpack);
    pack_b<<<4, 256, 0, stream>>>(bfp, bip, bgp, bop, bias);
    init_k<<<256, 256, 0, stream>>>(hxp);

    void* kargs[6] = {(void*)&X, (void*)&Wpack, (void*)&bias,
                      (void*)&hxp, (void*)&hist, (void*)&out};
    hipLaunchCooperativeKernel((const void*)lstm_persist, dim3(GRIDN), dim3(256),
                               kargs, 0, stream);

    probs_k<<<32768, 256, 0, stream>>>(hist, Wc, bc, out);
}

// Round 8
// 1183.448 us; speedup vs baseline: 18.8370x; 1.1023x over previous
//
#include <hip/hip_runtime.h>
#include <hip/hip_bf16.h>

// QLSTM: T=512, B=256, D=128, H=256.  z = [x,h] @ W^T + b, W=[4H,384]
// Round 8: round-6 adaptive XCD-local exchange, with the poll expressed as
// round-4's PROVEN fused asm idiom (4x global_load_dwordx4 + s_waitcnt in ONE
// asm block -> no tied-operand encoding, no in-flight VGPR hazard).
//  - Producer dual-stores tagged h-word: fast plane (plain store -> producer
//    XCD L2) + slow plane (sc1 -> IF, the round-4 proven path).
//  - Consumer: bounded fast poll (sc0, NPOLL tries) then sc1 fallback which
//    always succeeds -> liveness independent of workgroup->XCD mapping.
//  - Chain = blocks with equal (blockIdx % 16): same-XCD under round-robin.

#define T_STEPS 512
#define BATCH   256
#define DIN     128
#define HID     256
#define KDIM    384
#define LDK     392   // padded LDS row stride (shorts)
#define GRIDN   256
#define NPOLL   96    // bounded fast-poll tries before sc1 fallback

typedef __attribute__((ext_vector_type(8))) short short8;
typedef __attribute__((ext_vector_type(4))) short short4v;
typedef __attribute__((ext_vector_type(4))) float f32x4;

__device__ __forceinline__ unsigned short f2bf(float f) {
    unsigned u = __float_as_uint(f);
    unsigned r = (u + 0x7FFFu + ((u >> 16) & 1u)) >> 16;
    return (unsigned short)r;
}
__device__ __forceinline__ float bf2f(unsigned short s) {
    return __uint_as_float(((unsigned)s) << 16);
}
__device__ __forceinline__ float sigmoid_f(float x) {
    return 1.f / (1.f + __expf(-x));
}
__device__ __forceinline__ float tanh_f(float x) {
    float e = __expf(2.f * x);
    return 1.f - 2.f / (e + 1.f);
}
// ---- fused poll loads: 4 x dwordx4 + waitcnt in ONE asm block (round-4 idiom)
__device__ __forceinline__ void poll_load_sc0(const unsigned int* p, uint4& a,
                                              uint4& b, uint4& c, uint4& d) {
    asm volatile(
        "global_load_dwordx4 %0, %4, off sc0\n\t"
        "global_load_dwordx4 %1, %4, off offset:16 sc0\n\t"
        "global_load_dwordx4 %2, %4, off offset:32 sc0\n\t"
        "global_load_dwordx4 %3, %4, off offset:48 sc0\n\t"
        "s_waitcnt vmcnt(0)"
        : "=&v"(a), "=&v"(b), "=&v"(c), "=&v"(d) : "v"(p) : "memory");
}
__device__ __forceinline__ void poll_load_sc1(const unsigned int* p, uint4& a,
                                              uint4& b, uint4& c, uint4& d) {
    asm volatile(
        "global_load_dwordx4 %0, %4, off sc1\n\t"
        "global_load_dwordx4 %1, %4, off offset:16 sc1\n\t"
        "global_load_dwordx4 %2, %4, off offset:32 sc1\n\t"
        "global_load_dwordx4 %3, %4, off offset:48 sc1\n\t"
        "s_waitcnt vmcnt(0)"
        : "=&v"(a), "=&v"(b), "=&v"(c), "=&v"(d) : "v"(p) : "memory");
}
__device__ __forceinline__ void store_plain_u32(unsigned int* p, unsigned int v) {
    asm volatile("global_store_dword %0, %1, off" :: "v"(p), "v"(v) : "memory");
}
__device__ __forceinline__ void store_sc1_u32(unsigned int* p, unsigned int v) {
    asm volatile("global_store_dword %0, %1, off sc1" :: "v"(p), "v"(v) : "memory");
}
__device__ __forceinline__ unsigned pack2bf(unsigned lo, unsigned hi) {
    return (hi & 0xFFFF0000u) | (lo >> 16);
}
__device__ __forceinline__ bool tags_ok(const uint4& a, const uint4& b,
                                        const uint4& c, const uint4& d,
                                        unsigned tag) {
    return ((a.x ^ tag) & 0xFFFFu) == 0 && ((a.y ^ tag) & 0xFFFFu) == 0 &&
           ((a.z ^ tag) & 0xFFFFu) == 0 && ((a.w ^ tag) & 0xFFFFu) == 0 &&
           ((b.x ^ tag) & 0xFFFFu) == 0 && ((b.y ^ tag) & 0xFFFFu) == 0 &&
           ((b.z ^ tag) & 0xFFFFu) == 0 && ((b.w ^ tag) & 0xFFFFu) == 0 &&
           ((c.x ^ tag) & 0xFFFFu) == 0 && ((c.y ^ tag) & 0xFFFFu) == 0 &&
           ((c.z ^ tag) & 0xFFFFu) == 0 && ((c.w ^ tag) & 0xFFFFu) == 0 &&
           ((d.x ^ tag) & 0xFFFFu) == 0 && ((d.y ^ tag) & 0xFFFFu) == 0 &&
           ((d.z ^ tag) & 0xFFFFu) == 0 && ((d.w ^ tag) & 0xFFFFu) == 0;
}

// ---- pack weights: Wpack[n][k] bf16, n = g*256 + j, row-major [1024][384] ----
__global__ __launch_bounds__(256) void pack_w(
    const float* __restrict__ Wf, const float* __restrict__ Wi,
    const float* __restrict__ Wg, const float* __restrict__ Wo,
    unsigned short* __restrict__ Wp) {
    int idx = blockIdx.x * 256 + threadIdx.x;
    int n = idx / KDIM;
    int k = idx - n * KDIM;
    int g = n >> 8, j = n & 255;
    const float* s = (g == 0) ? Wf : (g == 1) ? Wi : (g == 2) ? Wg : Wo;
    Wp[idx] = f2bf(s[j * KDIM + k]);
}

__global__ __launch_bounds__(256) void pack_b(
    const float* __restrict__ bf, const float* __restrict__ bi,
    const float* __restrict__ bg, const float* __restrict__ bo,
    float* __restrict__ bp) {
    int n = blockIdx.x * 256 + threadIdx.x;
    int g = n >> 8, j = n & 255;
    const float* s = (g == 0) ? bf : (g == 1) ? bi : (g == 2) ? bg : bo;
    bp[n] = s[j];
}

// ---- zero all 4 exchange planes: fast[2] + slow[2] (h_0 = 0, tag 0) ----
__global__ __launch_bounds__(256) void init_k(unsigned int* __restrict__ hxp) {
    int tid = blockIdx.x * 256 + threadIdx.x;   // grid 256 -> 65536
    hxp[tid] = 0u;
    hxp[65536 + tid] = 0u;
    hxp[131072 + tid] = 0u;
    hxp[196608 + tid] = 0u;
}

// ---- persistent LSTM: all 512 steps in one launch ----
__global__ __launch_bounds__(256, 1) void lstm_persist(
    const float* __restrict__ X,            // [T,B,D] fp32
    const unsigned short* __restrict__ W,   // [1024][384] bf16
    const float* __restrict__ bias,         // [1024]
    unsigned int* __restrict__ hxp,         // fast[2][B][H] + slow[2][B][H]
    unsigned short* __restrict__ hist,      // [T][B][H] bf16
    float* __restrict__ out) {
    __shared__ __align__(16) unsigned short W_s[64 * LDK];    // 50176 B
    __shared__ __align__(16) unsigned short comb_s[16 * LDK]; // 12544 B
    __shared__ __align__(16) float z_s[4 * 272];              // 4352 B
    __shared__ int fastok_s;

    const int tid = threadIdx.x;
    // chain = same (blockIdx % 16): XCD-local under round-robin dispatch
    const int bg = blockIdx.x & 15, jg = blockIdx.x >> 4;
    const int b0 = bg * 16, j0 = jg * 16;
    const int wave = tid >> 6, lane = tid & 63;
    const int l16 = lane & 15, quad = lane >> 4;
    const int bi = tid >> 4, jj = tid & 15;
    const int b = b0 + bi, j = j0 + jj;

    // stage W tile once: local row = g*16+jr <- global row g*256+j0+jr ; 64x384
#pragma unroll
    for (int c = 0; c < 12; ++c) {
        int q = c * 256 + tid;
        int row = q / 48, c8 = q - row * 48;
        int g = row >> 4, jr = row & 15;
        short8 v = *(const short8*)(W + ((g * 256 + j0 + jr) * KDIM + c8 * 8));
        *(short8*)(&W_s[row * LDK + c8 * 8]) = v;
    }
    const float bs0 = bias[0 * HID + j];
    const float bs1 = bias[1 * HID + j];
    const float bs2 = bias[2 * HID + j];
    const float bs3 = bias[3 * HID + j];
    if (tid == 0) fastok_s = 1;

    float c_reg = 0.f;
    float h_final = 0.f;

    const unsigned short* arow = &comb_s[l16 * LDK + quad * 8];
    const unsigned short* brow = &W_s[(wave * 16 + l16) * LDK + quad * 8];
    const int hrow = tid >> 4, hc = tid & 15;
    const int xr0 = tid >> 5, xc4 = tid & 31, xr1 = (tid + 256) >> 5;

    // prefetch x_0
    const float* xb = X + b0 * DIN;
    float4 xv0 = *(const float4*)(xb + xr0 * DIN + xc4 * 4);
    float4 xv1 = *(const float4*)(xb + xr1 * DIN + xc4 * 4);

    __syncthreads();

    for (int k = 0; k < T_STEPS; ++k) {
        const unsigned tag = (unsigned)k;
        const unsigned int* fb =
            hxp + (k & 1) * 65536 + (b0 + hrow) * HID + hc * 16;
        const unsigned int* sb = fb + 131072;    // slow plane
        uint4 a, bq, cq, d;
        const int usefast = fastok_s;            // racy read is fine (hint only)

        // ---- stage x_k from prefetched regs ----
        {
            short4v r;
            r.x = (short)f2bf(xv0.x); r.y = (short)f2bf(xv0.y);
            r.z = (short)f2bf(xv0.z); r.w = (short)f2bf(xv0.w);
            *(short4v*)(&comb_s[xr0 * LDK + xc4 * 4]) = r;
            r.x = (short)f2bf(xv1.x); r.y = (short)f2bf(xv1.y);
            r.z = (short)f2bf(xv1.z); r.w = (short)f2bf(xv1.w);
            *(short4v*)(&comb_s[xr1 * LDK + xc4 * 4]) = r;
        }

        // ---- poll h_k: fast (bounded) then slow (guaranteed) ----
        if (usefast) {
            int tries = NPOLL;
            bool ok = false;
            for (;;) {
                poll_load_sc0(fb, a, bq, cq, d);
                if (tags_ok(a, bq, cq, d, tag)) { ok = true; break; }
                if (--tries == 0) break;
            }
            if (!ok) {                       // bounded fallback: ALWAYS succeeds
                fastok_s = 0;
                for (;;) {
                    poll_load_sc1(sb, a, bq, cq, d);
                    if (tags_ok(a, bq, cq, d, tag)) break;
                    __builtin_amdgcn_s_sleep(1);
                }
            }
        } else {
            for (;;) {
                poll_load_sc1(sb, a, bq, cq, d);
                if (tags_ok(a, bq, cq, d, tag)) break;
                __builtin_amdgcn_s_sleep(1);
            }
        }

        // extract 16 bf16 -> comb_s[hrow][DIN + hc*16 ..]
        {
            uint4 p0, p1;
            p0.x = pack2bf(a.x, a.y);   p0.y = pack2bf(a.z, a.w);
            p0.z = pack2bf(bq.x, bq.y); p0.w = pack2bf(bq.z, bq.w);
            p1.x = pack2bf(cq.x, cq.y); p1.y = pack2bf(cq.z, cq.w);
            p1.z = pack2bf(d.x, d.y);   p1.w = pack2bf(d.z, d.w);
            *(uint4*)(&comb_s[hrow * LDK + DIN + hc * 16]) = p0;
            *(uint4*)(&comb_s[hrow * LDK + DIN + hc * 16 + 8]) = p1;
        }
        __syncthreads();

        // ---- MFMA: z_gate = comb[16x384] * Wg^T, 2 acc chains ----
        f32x4 acc0 = {0.f, 0.f, 0.f, 0.f}, acc1 = {0.f, 0.f, 0.f, 0.f};
#pragma unroll
        for (int kt = 0; kt < 6; ++kt) {
            short8 a0 = *(const short8*)(arow + (2 * kt) * 32);
            short8 b0v = *(const short8*)(brow + (2 * kt) * 32);
            short8 a1 = *(const short8*)(arow + (2 * kt + 1) * 32);
            short8 b1v = *(const short8*)(brow + (2 * kt + 1) * 32);
            acc0 = __builtin_amdgcn_mfma_f32_16x16x32_bf16(a0, b0v, acc0, 0, 0, 0);
            acc1 = __builtin_amdgcn_mfma_f32_16x16x32_bf16(a1, b1v, acc1, 0, 0, 0);
        }
#pragma unroll
        for (int r = 0; r < 4; ++r)
            z_s[wave * 272 + (quad * 4 + r) * 17 + l16] = acc0[r] + acc1[r];
        __syncthreads();

        // ---- gates; h dual-store FIRST (critical), then hist + x prefetch ----
        float zf = z_s[0 * 272 + bi * 17 + jj] + bs0;
        float zi = z_s[1 * 272 + bi * 17 + jj] + bs1;
        float zg = z_s[2 * 272 + bi * 17 + jj] + bs2;
        float zo = z_s[3 * 272 + bi * 17 + jj] + bs3;
        float fg = sigmoid_f(zf);
        float ig = sigmoid_f(zi);
        float gg = tanh_f(zg);
        float og = sigmoid_f(zo);
        c_reg = fg * c_reg + ig * gg;
        float hval = og * tanh_f(c_reg);
        unsigned short hb = f2bf(hval);
        unsigned int hword = ((unsigned)hb << 16) | (unsigned)(k + 1);
        unsigned int* fdst = hxp + ((k + 1) & 1) * 65536 + b * HID + j;
        store_plain_u32(fdst, hword);             // fast plane (producer's L2)
        store_sc1_u32(fdst + 131072, hword);      // slow plane (IF, proven path)
        hist[(size_t)k * BATCH * HID + b * HID + j] = hb;
        if (k + 1 < T_STEPS) {
            const float* xn = X + (size_t)(k + 1) * BATCH * DIN + b0 * DIN;
            xv0 = *(const float4*)(xn + xr0 * DIN + xc4 * 4);
            xv1 = *(const float4*)(xn + xr1 * DIN + xc4 * 4);
        } else {
            h_final = hval;
        }
    }

    // epilogue: hx (fp32) and cx outputs
    out[T_STEPS * BATCH * 2 + b * HID + j] = h_final;
    out[T_STEPS * BATCH * 2 + BATCH * HID + b * HID + j] = c_reg;
}

// ---- classifier head: one wave per (t,b) row ----
__global__ __launch_bounds__(256) void probs_k(
    const unsigned short* __restrict__ hist, const float* __restrict__ Wc,
    const float* __restrict__ bc, float* __restrict__ out) {
    const int wave = threadIdx.x >> 6, lane = threadIdx.x & 63;
    const size_t row = (size_t)blockIdx.x * 4 + wave;   // row = t*256+b < 131072
    const unsigned short* h = hist + row * HID;
    short4v hv = *(const short4v*)(h + lane * 4);
    const float4 wv = *(const float4*)(Wc + lane * 4);
    float p = bf2f((unsigned short)hv.x) * wv.x + bf2f((unsigned short)hv.y) * wv.y +
              bf2f((unsigned short)hv.z) * wv.z + bf2f((unsigned short)hv.w) * wv.w;
#pragma unroll
    for (int off = 32; off >= 1; off >>= 1) p += __shfl_down(p, off);
    if (lane == 0) {
        float prob = 1.f / (1.f + __expf(-(p + bc[0])));
        out[row * 2]     = prob;
        out[row * 2 + 1] = 1.f - prob;
    }
}

extern "C" void kernel_launch(void* const* d_in, const int* in_sizes, int n_in,
                              void* d_out, int out_size, void* d_ws, size_t ws_size,
                              hipStream_t stream) {
    const float* X  = (const float*)d_in[0];
    const float* Wf = (const float*)d_in[1];
    const float* bfp= (const float*)d_in[2];
    const float* Wi = (const float*)d_in[3];
    const float* bip= (const float*)d_in[4];
    const float* Wg = (const float*)d_in[5];
    const float* bgp= (const float*)d_in[6];
    const float* Wo = (const float*)d_in[7];
    const float* bop= (const float*)d_in[8];
    const float* Wc = (const float*)d_in[9];
    const float* bc = (const float*)d_in[10];
    float* out = (float*)d_out;

    char* ws = (char*)d_ws;
    unsigned short* Wpack = (unsigned short*)(ws);               // 786432 B
    float* bias = (float*)(ws + 786432);                         // 4096 B
    unsigned int* hxp = (unsigned int*)(ws + 790528);            // 1048576 B
    unsigned short* hist = (unsigned short*)(ws + 1839104);      // 67108864 B

    pack_w<<<1536, 256, 0, stream>>>(Wf, Wi, Wg, Wo, Wpack);
    pack_b<<<4, 256, 0, stream>>>(bfp, bip, bgp, bop, bias);
    init_k<<<256, 256, 0, stream>>>(hxp);

    void* kargs[6] = {(void*)&X, (void*)&Wpack, (void*)&bias,
                      (void*)&hxp, (void*)&hist, (void*)&out};
    (void)hipLaunchCooperativeKernel((const void*)lstm_persist, dim3(GRIDN),
                                     dim3(256), kargs, 0, stream);

    probs_k<<<32768, 256, 0, stream>>>(hist, Wc, bc, out);
}